// Round 10
// baseline (388.318 us; speedup 1.0000x reference)
//
#include <hip/hip_runtime.h>
#include <math.h>

// LSTM B=8192,T=512,IN=3,H=32,OUT=2 fp32.
// R18 = R17 with the stream-B prefetch off-by-one fixed.
// R17 bug: both streams used tn = t+2 for the held-x prefetch. Stream A's
// xp is computed in halfO one FULL iteration before its MFMA (distance 2
// correct); stream B's xp is computed in halfE of the SAME iteration as
// MFMA_B (halfO), so the prefetch written in halfE of iter t is consumed at
// iter t+1 halfE -> must be x_B(t+1). tn=t+2 shifted stream B's inputs by
// one timestep (absmax 8.3e-2). Fix: tb = t+1 for B.
// Structure (unchanged): criss-cross dual-stream at 2 waves/SIMD. 8-wave
// blocks (512 thr), 32 batches (streams A,B of 16), wave w owns chunk w =
// units 4w..4w+3 for both streams (A-frag shared). Lane (n,q) owns unit
// 4w+q of batch n, scalar gates (7 trans + ~15 VALU).
//   halfE(t): read BfragA(t-1) | gates_B(t-1)+write | MFMA_A(t) | xpB(t) | bar
//   halfO(t): read BfragB(t-1) | gates_A(t)+write  | MFMA_B(t) | xpA(t+1)| bar
// Every ds_read / MFMA-chain / trans-chain crosses a half of independent
// work (intra-wave ILP) AND a partner wave fills residual holes (TLP).
// grid 256 x 512 thr -> 1 block/CU, 2 waves/SIMD.
// A-perm (R14-verified): A row m -> W row 32*(m&3) + 4w + (m>>2)
//   => acc[r] = gate r of unit 4w+q. Zero selects, zero cross-lane.
// lgkm-only barriers; single-buffer LDS per stream (reads drained at the
// barrier, overwrite 2 halves later). h(-1)=0 folds into acc = xp.

namespace {
constexpr int   kT   = 512;
constexpr float kL2E = 1.44269504088896340736f;
}

typedef __bf16 bf16x8 __attribute__((ext_vector_type(8)));
typedef float  f32x4  __attribute__((ext_vector_type(4)));
typedef unsigned int u32x4 __attribute__((ext_vector_type(4)));

union Frag {
    bf16x8 v;
    unsigned short u[8];
    unsigned int   d[4];
    u32x4          q4;
};

__device__ __forceinline__ unsigned short bf_rne(float f) {
    unsigned u = __float_as_uint(f);
    u += 0x7fffu + ((u >> 16) & 1u);
    return (unsigned short)(u >> 16);
}
__device__ __forceinline__ float bf_tof(unsigned short h) {
    return __uint_as_float((unsigned)h << 16);
}
__device__ __forceinline__ float fast_exp2(float v) { return __builtin_amdgcn_exp2f(v); }
__device__ __forceinline__ float fast_rcp(float v)  { return __builtin_amdgcn_rcpf(v); }

// lgkmcnt-only barrier: ds ops drained, global loads stay in flight.
__device__ __forceinline__ void lgkm_barrier() {
    asm volatile("s_waitcnt lgkmcnt(0)" ::: "memory");
    __builtin_amdgcn_s_barrier();
    asm volatile("" ::: "memory");
}

#define MFMA16 __builtin_amdgcn_mfma_f32_16x16x32_bf16

extern "C" __global__ __launch_bounds__(512, 2)
void lstm_xx3(const float* __restrict__ x,
              const float* __restrict__ W_ih,
              const float* __restrict__ W_hh,
              const float* __restrict__ b_ih,
              const float* __restrict__ b_hh,
              const float* __restrict__ W_fc,
              const float* __restrict__ b_fc,
              float* __restrict__ out) {
    const int tid  = threadIdx.x;
    const int lane = tid & 63;
    const int w    = tid >> 6;          // wave id 0..7: owns chunk w
    const int n    = lane & 15;         // batch-within-stream == B/D column
    const int q    = lane >> 4;         // k-quad / D row group
    const int bid  = blockIdx.x;
    const int bA   = bid * 32 + n;      // stream A batch
    const int bB   = bA + 16;           // stream B batch

    // single-buffered h planes per stream: [stream][hi/lo][batch][unit+pad]
    __shared__ __align__(16) unsigned short lds_h[2][2][16][40];

    // ---- A frag (chunk w): A row m -> W row R(m) = 32*(m&3) + 4w + (m>>2).
    // HW: A row = lane&15 (=n), k = 8q+j; D col = lane&15, row = 4q+reg.
    // => acc[r] = gate r of unit u0 = 4w + q.  (R14-verified)
    Frag Ah, Al;
    {
        const int   g = n & 3;
        const float s = (g == 2) ? -2.0f * kL2E : -kL2E;
        const int   R = 32 * g + 4 * w + (n >> 2);
#pragma unroll
        for (int j = 0; j < 8; ++j) {
            const float wv = W_hh[R * 32 + 8 * q + j] * s;
            const unsigned short hb = bf_rne(wv);
            Ah.u[j] = hb;
            Al.u[j] = bf_rne(wv - bf_tof(hb));
        }
    }

    // ---- x-path constants: my unit u0 = 4w+q, 4 gates (scalar) ----
    const int u0 = 4 * w + q;
    float xw[4][3], xbias[4];
#pragma unroll
    for (int g = 0; g < 4; ++g) {
        const float s = (g == 2) ? -2.0f * kL2E : -kL2E;
        const int   R = 32 * g + u0;
#pragma unroll
        for (int k = 0; k < 3; ++k) xw[g][k] = W_ih[R * 3 + k] * s;
        xbias[g] = (b_ih[R] + b_hh[R]) * s;
    }

    const float* xA = x + (size_t)bA * kT * 3;
    const float* xB = x + (size_t)bB * kT * 3;

    float cstA = 0.f, cstB = 0.f;
    Frag BhA, BlA, BhB, BlB;

    // scalar gate math (R14-identical): acc[r] = gate r of my unit
    auto gates = [&](const f32x4& a, float& cst) -> float {
        const float Ei = fast_exp2(a[0]);
        const float Ef = fast_exp2(a[1]);
        const float Eg = fast_exp2(a[2]);
        const float Eo = fast_exp2(a[3]);
        const float pf  = 1.0f + Ef;
        const float pi  = 1.0f + Ei;
        const float pg  = 1.0f + Eg;
        const float tig = pi * pg;
        const float den = tig * pf;
        const float num = fmaf(cst, tig, (1.0f - Eg) * pf);
        const float c   = num * fast_rcp(den);
        cst = c;
        float Ec = fast_exp2(c * (-2.0f * kL2E));
        Ec = fminf(Ec, 1e30f);
        const float od = (1.0f + Eo) * (1.0f + Ec);
        return (1.0f - Ec) * fast_rcp(od);
    };
    auto packwrite = [&](float h, int s) {
        const unsigned short hi = bf_rne(h);
        const unsigned short lo = bf_rne(h - bf_tof(hi));
        lds_h[s][0][n][u0] = hi;
        lds_h[s][1][n][u0] = lo;
    };
    auto xpf = [&](float x0, float x1, float x2) -> f32x4 {
        f32x4 r;
#pragma unroll
        for (int g = 0; g < 4; ++g)
            r[g] = fmaf(x0, xw[g][0],
                   fmaf(x1, xw[g][1],
                   fmaf(x2, xw[g][2], xbias[g])));
        return r;
    };

    // ---- prologue ----
    f32x4 xpA = xpf(xA[0], xA[1], xA[2]);     // xp_A(0)
    f32x4 xpB = xpf(xB[0], xB[1], xB[2]);     // xp_B(0)
    float hA0 = xA[3], hA1 = xA[4], hA2 = xA[5];   // x_A(1)
    float hB0 = xB[3], hB1 = xB[4], hB2 = xB[5];   // x_B(1)

    // t=0: h(-1)=0 => acc = xp (D = A*0 + C)
    f32x4 accA = xpA;
    f32x4 accB = xpB;
    packwrite(gates(accA, cstA), 0);          // h_A(0) -> LDS
    xpA = xpf(hA0, hA1, hA2);                 // xp_A(1)
    hA0 = xA[6]; hA1 = xA[7]; hA2 = xA[8];    // x_A(2)
    lgkm_barrier();

    // ---- main loop: t = 1..511 ----
    // Invariants at loop top:
    //   xpA = xp_A(t);  hA = x_A(t+1)  (A: distance-2 prefetch via halfO)
    //   accB = acc_B(t-1); hB = x_B(t) (B: distance-1 prefetch via halfE)
    for (int t = 1; t < kT; ++t) {
        const int tn = (t + 2 < kT) ? t + 2 : kT - 1;   // stream A prefetch
        const int tb = (t + 1 < kT) ? t + 1 : kT - 1;   // stream B prefetch

        // ===== halfE: read BfragA(t-1) | gates_B(t-1) | MFMA_A(t) | xpB(t) =====
        BhA.q4 = *(const u32x4*)&lds_h[0][0][n][8 * q];
        BlA.q4 = *(const u32x4*)&lds_h[0][1][n][8 * q];

        packwrite(gates(accB, cstB), 1);      // h_B(t-1) -> LDS

        accA = MFMA16(Ah.v, BhA.v, xpA, 0, 0, 0);
        accA = MFMA16(Al.v, BhA.v, accA, 0, 0, 0);
        accA = MFMA16(Ah.v, BlA.v, accA, 0, 0, 0);

        xpB = xpf(hB0, hB1, hB2);             // xp_B(t) from x_B(t)
        hB0 = xB[tb * 3 + 0];                 // x_B(t+1)  [the R18 fix]
        hB1 = xB[tb * 3 + 1];
        hB2 = xB[tb * 3 + 2];

        lgkm_barrier();

        // ===== halfO: read BfragB(t-1) | gates_A(t) | MFMA_B(t) | xpA(t+1) =====
        BhB.q4 = *(const u32x4*)&lds_h[1][0][n][8 * q];
        BlB.q4 = *(const u32x4*)&lds_h[1][1][n][8 * q];

        packwrite(gates(accA, cstA), 0);      // h_A(t) -> LDS

        accB = MFMA16(Ah.v, BhB.v, xpB, 0, 0, 0);
        accB = MFMA16(Al.v, BhB.v, accB, 0, 0, 0);
        accB = MFMA16(Ah.v, BlB.v, accB, 0, 0, 0);

        xpA = xpf(hA0, hA1, hA2);             // xp_A(t+1) from x_A(t+1)
        hA0 = xA[tn * 3 + 0];                 // x_A(t+2)
        hA1 = xA[tn * 3 + 1];
        hA2 = xA[tn * 3 + 2];

        lgkm_barrier();
    }

    // ---- tail: gates_B(511) -> h_B(511) ----
    packwrite(gates(accB, cstB), 1);
    lgkm_barrier();

    // ---- epilogue: wave 0 -> stream A, wave 1 -> stream B ----
    if (w < 2) {
        const int set = w;
        const int bb  = bid * 32 + set * 16 + n;
        Frag Hh, Hl;
        Hh.q4 = *(const u32x4*)&lds_h[set][0][n][8 * q];
        Hl.q4 = *(const u32x4*)&lds_h[set][1][n][8 * q];
        float s0 = 0.f, s1 = 0.f;
#pragma unroll
        for (int j = 0; j < 8; ++j) {
            const float hv = bf_tof(Hh.u[j]) + bf_tof(Hl.u[j]);
            const int   u  = 8 * q + j;
            s0 = fmaf(hv, W_fc[u], s0);
            s1 = fmaf(hv, W_fc[32 + u], s1);
        }
        s0 += __shfl_xor(s0, 16, 64); s1 += __shfl_xor(s1, 16, 64);
        s0 += __shfl_xor(s0, 32, 64); s1 += __shfl_xor(s1, 32, 64);
        if (lane < 16) {
            out[(size_t)bb * 2 + 0] = s0 + b_fc[0];
            out[(size_t)bb * 2 + 1] = s1 + b_fc[1];
        }
    }
}

extern "C" void kernel_launch(void* const* d_in, const int* in_sizes, int n_in,
                              void* d_out, int out_size, void* d_ws, size_t ws_size,
                              hipStream_t stream) {
    const float* x    = (const float*)d_in[0];
    const float* W_ih = (const float*)d_in[1];
    const float* W_hh = (const float*)d_in[2];
    const float* b_ih = (const float*)d_in[3];
    const float* b_hh = (const float*)d_in[4];
    const float* W_fc = (const float*)d_in[5];
    const float* b_fc = (const float*)d_in[6];
    float* out = (float*)d_out;

    const int batch = in_sizes[0] / (kT * 3);   // 8192
    dim3 grid(batch / 32);                      // 256 blocks of 8 waves
    dim3 block(512);                            // -> 1 block/CU, 2 waves/SIMD
    hipLaunchKernelGGL(lstm_xx3, grid, block, 0, stream,
                       x, W_ih, W_hh, b_ih, b_hh, W_fc, b_fc, out);
}

// Round 11
// 276.024 us; speedup vs baseline: 1.4068x; 1.4068x over previous
//
#include <hip/hip_runtime.h>
#include <math.h>

// LSTM B=8192,T=512,IN=3,H=32,OUT=2 fp32.
// R19 = R13 chassis (the measured optimum: 4-wave blocks, pk gates,
// 1 barrier/step, 2 independent blocks/CU) with two cuts:
// 1) h_lo dropped (2-pass MFMA: Ah*Bh + Al*Bh). W-lo kept (static weight
//    quantization = systematic bias); h-lo dropped (fresh per-step rounding
//    noise, random-walks). Kills 2 MFMA/wave-step, shortens the MFMA chain
//    3->2, and deletes the whole lo pipeline (cvt_pk, 2 subs, ds_write,
//    ds_read_b128 per wave-step; LDS traffic and bank conflicts halve).
// 2) lgkm-only barrier (R18-verified primitive): __syncthreads drains
//    vmcnt(0), stalling on in-flight x-prefetch HBM loads; s_waitcnt
//    lgkmcnt(0) + s_barrier lets them ride across the barrier.
//    Race-free with double-buffered LDS + 1 barrier/step: ds reads drain at
//    each barrier, a buffer's overwrite is 2 barriers after its last read.
// R18 post-mortem: criss-cross @2w/SIMD failed (361us) -- 1 block/CU means
// both co-resident waves share the same barrier -> phase-lock; R13's
// 2-independent-blocks/CU + 1 barrier/step is the right interleave source.
// Unchanged from R13: adjacent-unit A-perm R(m)=32*(m&3)+8w+2*(m>>2)+c
// (lane's units u0=8w+2q, u0+1; acc_c[r] = gate r, zero selects), pk-f32x2
// gate math w/ fused triple-rcp, exact fp32 xp in MFMA C, cvt_pk h-pack,
// block-parity s_sleep stagger, grid 512 x 256thr.

namespace {
constexpr int   kT      = 512;
constexpr float kL2E    = 1.44269504088896340736f;
constexpr int   kStride = 40;   // ushorts per LDS row: 32 units + 8 pad
}

typedef __bf16 bf16x8 __attribute__((ext_vector_type(8)));
typedef float  f32x4  __attribute__((ext_vector_type(4)));
typedef float  f32x2  __attribute__((ext_vector_type(2)));
typedef unsigned int u32x4 __attribute__((ext_vector_type(4)));

union Frag {
    bf16x8 v;
    unsigned short u[8];
    unsigned int   d[4];
    u32x4          q4;
};

__device__ __forceinline__ unsigned short bf_rne(float f) {
    unsigned u = __float_as_uint(f);
    u += 0x7fffu + ((u >> 16) & 1u);
    return (unsigned short)(u >> 16);
}
__device__ __forceinline__ float bf_tof(unsigned short h) {
    return __uint_as_float((unsigned)h << 16);
}
__device__ __forceinline__ float fast_exp2(float v) { return __builtin_amdgcn_exp2f(v); }
__device__ __forceinline__ float fast_rcp(float v)  { return __builtin_amdgcn_rcpf(v); }

// v_cvt_pk_bf16_f32: dst = [lo16 = bf16_rne(a), hi16 = bf16_rne(b)]
__device__ __forceinline__ unsigned cvt_pk_bf16(float a, float b) {
    unsigned r;
    asm("v_cvt_pk_bf16_f32 %0, %1, %2" : "=v"(r) : "v"(a), "v"(b));
    return r;
}

__device__ __forceinline__ f32x2 fma2(f32x2 a, f32x2 b, f32x2 c) {
    return __builtin_elementwise_fma(a, b, c);
}
__device__ __forceinline__ f32x2 exp22(f32x2 v) {
    f32x2 r = {fast_exp2(v.x), fast_exp2(v.y)};
    return r;
}
__device__ __forceinline__ f32x2 rcp2(f32x2 v) {
    f32x2 r = {fast_rcp(v.x), fast_rcp(v.y)};
    return r;
}
__device__ __forceinline__ f32x2 sp2(float v) {
    f32x2 r = {v, v};
    return r;
}

// lgkmcnt-only barrier: ds ops drained, global loads stay in flight.
__device__ __forceinline__ void lgkm_barrier() {
    asm volatile("s_waitcnt lgkmcnt(0)" ::: "memory");
    __builtin_amdgcn_s_barrier();
    asm volatile("" ::: "memory");
}

#define MFMA16 __builtin_amdgcn_mfma_f32_16x16x32_bf16

extern "C" __global__ __launch_bounds__(256, 2)
void lstm_s2p(const float* __restrict__ x,
              const float* __restrict__ W_ih,
              const float* __restrict__ W_hh,
              const float* __restrict__ b_ih,
              const float* __restrict__ b_hh,
              const float* __restrict__ W_fc,
              const float* __restrict__ b_fc,
              float* __restrict__ out) {
    const int tid  = threadIdx.x;
    const int lane = tid & 63;
    const int w    = tid >> 6;          // wave id 0..3
    const int n    = lane & 15;         // batch-within-block == B/D column
    const int q    = lane >> 4;         // k-quad / D row group
    const int bid  = blockIdx.x;
    const int batch = bid * 16 + n;

    // double-buffered h plane (hi only): [buf][batch][unit+pad]
    __shared__ __align__(16) unsigned short lds_h[2][16][kStride];

    // ---- A frags: chunk c, A row m -> W row R(m) = 32*(m&3)+8w+2*(m>>2)+c.
    // HW: A row = lane&15 (=n), k = 8q+j; D col = lane&15, row = 4q+reg.
    // => acc_c[r] = gate r of unit u = 8w + 2q + c (ADJACENT units per lane).
    Frag Ah[2], Al[2];
#pragma unroll
    for (int c = 0; c < 2; ++c) {
        const int   g = n & 3;
        const float s = (g == 2) ? -2.0f * kL2E : -kL2E;
        const int   R = 32 * g + 8 * w + 2 * (n >> 2) + c;
#pragma unroll
        for (int j = 0; j < 8; ++j) {
            const float wv = W_hh[R * 32 + 8 * q + j] * s;
            const unsigned short hb = bf_rne(wv);
            Ah[c].u[j] = hb;
            Al[c].u[j] = bf_rne(wv - bf_tof(hb));
        }
    }

    // ---- x-path constants: units (u0, u0+1) x 4 gates, f32x2-paired ----
    const int u0 = 8 * w + 2 * q;
    f32x2 xwp[4][3], xbp[4];
#pragma unroll
    for (int g = 0; g < 4; ++g) {
        const float s  = (g == 2) ? -2.0f * kL2E : -kL2E;
        const int   R0 = 32 * g + u0, R1 = R0 + 1;
#pragma unroll
        for (int k = 0; k < 3; ++k) {
            f32x2 wv = {W_ih[R0 * 3 + k] * s, W_ih[R1 * 3 + k] * s};
            xwp[g][k] = wv;
        }
        f32x2 bb = {(b_ih[R0] + b_hh[R0]) * s, (b_ih[R1] + b_hh[R1]) * s};
        xbp[g] = bb;
    }

    const float* xb = x + (size_t)batch * kT * 3;

    f32x2 cst = {0.f, 0.f};
    Frag Bh;
#pragma unroll
    for (int j = 0; j < 4; ++j) Bh.d[j] = 0;

    // prologue: xpC = XP(0); xc = x(1)
    f32x4 xpC0, xpC1;
    {
        const float a0 = xb[0], a1 = xb[1], a2 = xb[2];
#pragma unroll
        for (int g = 0; g < 4; ++g) {
            f32x2 p = fma2(sp2(a0), xwp[g][0],
                      fma2(sp2(a1), xwp[g][1],
                      fma2(sp2(a2), xwp[g][2], xbp[g])));
            xpC0[g] = p.x;
            xpC1[g] = p.y;
        }
    }
    float xc0 = xb[3], xc1 = xb[4], xc2 = xb[5];

    // ---- block anti-phase stagger (one-time, ~half step) ----
    if ((bid ^ (bid >> 8)) & 1) {
        __builtin_amdgcn_s_sleep(8);
    }

    for (int t = 0; t < kT; ++t) {
        // ---- 4 MFMA: 2 indep depth-2 chains (W hi+lo x h hi), C carries xp
        f32x4 a0 = MFMA16(Ah[0].v, Bh.v, xpC0, 0, 0, 0);
        f32x4 a1 = MFMA16(Ah[1].v, Bh.v, xpC1, 0, 0, 0);
        a0 = MFMA16(Al[0].v, Bh.v, a0, 0, 0, 0);
        a1 = MFMA16(Al[1].v, Bh.v, a1, 0, 0, 0);

        // ---- shadow work: prefetch x(t+2), XP(t+1) from held x(t+1) ----
        const int tn = (t + 2 < kT) ? t + 2 : kT - 1;
        const float xn0 = xb[tn * 3 + 0];
        const float xn1 = xb[tn * 3 + 1];
        const float xn2 = xb[tn * 3 + 2];
#pragma unroll
        for (int g = 0; g < 4; ++g) {
            f32x2 p = fma2(sp2(xc0), xwp[g][0],
                      fma2(sp2(xc1), xwp[g][1],
                      fma2(sp2(xc2), xwp[g][2], xbp[g])));
            xpC0[g] = p.x;
            xpC1[g] = p.y;
        }

        // ---- gate math, f32x2 over (u0, u0+1): acc_c[r] = gate r ----
        const f32x2 one = {1.f, 1.f};
        f32x2 P0 = {a0[0], a1[0]};
        f32x2 P1 = {a0[1], a1[1]};
        f32x2 P2 = {a0[2], a1[2]};
        f32x2 P3 = {a0[3], a1[3]};
        f32x2 Ei = exp22(P0);
        f32x2 Ef = exp22(P1);
        f32x2 Eg = exp22(P2);
        f32x2 Eo = exp22(P3);
        f32x2 pf  = one + Ef;
        f32x2 pi  = one + Ei;
        f32x2 pg  = one + Eg;
        f32x2 tig = pi * pg;
        f32x2 den = tig * pf;
        f32x2 num = fma2(cst, tig, (one - Eg) * pf);
        f32x2 c   = num * rcp2(den);
        cst = c;
        f32x2 ca  = c * sp2(-2.0f * kL2E);
        f32x2 Ec  = exp22(ca);
        Ec.x = fminf(Ec.x, 1e30f);
        Ec.y = fminf(Ec.y, 1e30f);
        f32x2 od  = (one + Eo) * (one + Ec);
        f32x2 h2  = (one - Ec) * rcp2(od);

        // ---- pack: RNE bf16 pair via one cvt_pk, one ds_write_b32 ----
        const unsigned hh = cvt_pk_bf16(h2.x, h2.y);
        const int buf = t & 1;
        *(unsigned*)&lds_h[buf][n][u0] = hh;   // u0 even -> 4B aligned

        lgkm_barrier();

        // ---- B frag for next step: units 8q..8q+7 of batch n ----
        Bh.q4 = *(const u32x4*)&lds_h[buf][n][8 * q];

        xc0 = xn0; xc1 = xn1; xc2 = xn2;
    }

    // ---- epilogue (wave 0): h(511) is in lds buf 1 ----
    if (w == 0) {
        Frag Hh;
        Hh.q4 = *(const u32x4*)&lds_h[1][n][8 * q];
        float s0 = 0.f, s1 = 0.f;
#pragma unroll
        for (int j = 0; j < 8; ++j) {
            const float hv = bf_tof(Hh.u[j]);
            const int   u  = 8 * q + j;
            s0 = fmaf(hv, W_fc[u], s0);
            s1 = fmaf(hv, W_fc[32 + u], s1);
        }
        s0 += __shfl_xor(s0, 16, 64); s1 += __shfl_xor(s1, 16, 64);
        s0 += __shfl_xor(s0, 32, 64); s1 += __shfl_xor(s1, 32, 64);
        if (lane < 16) {
            out[(size_t)batch * 2 + 0] = s0 + b_fc[0];
            out[(size_t)batch * 2 + 1] = s1 + b_fc[1];
        }
    }
}

extern "C" void kernel_launch(void* const* d_in, const int* in_sizes, int n_in,
                              void* d_out, int out_size, void* d_ws, size_t ws_size,
                              hipStream_t stream) {
    const float* x    = (const float*)d_in[0];
    const float* W_ih = (const float*)d_in[1];
    const float* W_hh = (const float*)d_in[2];
    const float* b_ih = (const float*)d_in[3];
    const float* b_hh = (const float*)d_in[4];
    const float* W_fc = (const float*)d_in[5];
    const float* b_fc = (const float*)d_in[6];
    float* out = (float*)d_out;

    const int batch = in_sizes[0] / (kT * 3);   // 8192
    dim3 grid(batch / 16);                      // 512 blocks of 4 waves
    dim3 block(256);                            // -> 2 blocks/CU, 2 waves/SIMD
    hipLaunchKernelGGL(lstm_s2p, grid, block, 0, stream,
                       x, W_ih, W_hh, b_ih, b_hh, W_fc, b_fc, out);
}